// Round 13
// baseline (3626.147 us; speedup 1.0000x reference)
//
#include <hip/hip_runtime.h>
#include <hip/hip_cooperative_groups.h>

namespace cg = cooperative_groups;

typedef __bf16 bf16;
typedef __attribute__((ext_vector_type(8))) __bf16 bf16x8;
typedef __attribute__((ext_vector_type(4))) float f32x4;
typedef __attribute__((ext_vector_type(4))) unsigned short u16x4;

__device__ __forceinline__ void gload_lds16(const void* g, void* l) {
  __builtin_amdgcn_global_load_lds(
      (const __attribute__((address_space(1))) void*)g,
      (__attribute__((address_space(3))) void*)l, 16, 0, 0);
}

__device__ __forceinline__ float sigmoidf_(float x) { return 1.0f / (1.0f + expf(-x)); }

__device__ __forceinline__ float bf2f(unsigned short u) {
  union { unsigned int i; float f; } v;
  v.i = ((unsigned int)u) << 16;
  return v.f;
}
__device__ __forceinline__ unsigned short f2bfbits(float x) {
  union { bf16 b; unsigned short u; } v;
  v.b = (bf16)x;
  return v.u;
}

#define SB() __builtin_amdgcn_sched_barrier(0)
#define MFMA16(a, b, c) __builtin_amdgcn_mfma_f32_16x16x32_bf16(a, b, c, 0, 0, 0)

// ---------------------------------------------------------------------------
// Standalone 256x256 GEMM (r10 core): BK=32, ring-4 LDS, 1 barrier/K-tile,
// n-major XCD map. MODE 0 only here (bf16 X-layout store) — used for the two
// prologue GEMMs (Xz, E).
// ---------------------------------------------------------------------------
template<int MODE>
__global__ __launch_bounds__(512, 2)
void gemm8(const bf16* __restrict__ A, int lda,
           const bf16* __restrict__ Bw, int K,
           bf16* __restrict__ Cb) {
  extern __shared__ __align__(16) char smem_raw[];
  bf16* lsA = (bf16*)smem_raw;    // [4][256][32]
  bf16* lsB = lsA + 4 * 8192;

  const int tid = threadIdx.x;
  const int lane = tid & 63;
  const int wave = tid >> 6;
  const int wm = wave >> 2, wn = wave & 3;

  const int bid = blockIdx.x;
  const int wgid = (bid & 7) * 32 + (bid >> 3);
  const int m0 = (wgid & 15) * 256, n0 = (wgid >> 4) * 256;  // n-major

  const int nkt = K >> 5;

  const int srow = tid >> 2;
  const int scol = ((tid & 3) ^ ((srow >> 1) & 3)) * 8;
  const bf16* gAs = A + (size_t)(m0 + srow) * lda + scol;
  const bf16* gBs = Bw + (size_t)(n0 + srow) * K + scol;

  auto stA = [&](int kt) {
    bf16* d = lsA + (kt & 3) * 8192 + tid * 8;
    const bf16* s = gAs + (size_t)kt * 32;
    gload_lds16(s, d);
    gload_lds16(s + (size_t)128 * lda, d + 4096);
  };
  auto stB = [&](int kt) {
    bf16* d = lsB + (kt & 3) * 8192 + tid * 8;
    const bf16* s = gBs + (size_t)kt * 32;
    gload_lds16(s, d);
    gload_lds16(s + (size_t)128 * K, d + 4096);
  };

  const int sw = ((lane & 15) >> 1) & 3;
  const int rslot = ((lane >> 4) ^ sw) * 8;
  const int abase = (wm * 128 + (lane & 15)) * 32 + rslot;
  const int bbase = (wn * 64 + (lane & 15)) * 32 + rslot;

  f32x4 acc[8][4] = {};

  stA(0); stB(0); stA(1); stB(1);
  asm volatile("s_waitcnt vmcnt(4)" ::: "memory");

  for (int t = 0; t < nkt; ++t) {
    SB();
    __builtin_amdgcn_s_barrier();
    SB();
    const bf16* pA = lsA + (t & 3) * 8192;
    const bf16* pB = lsB + (t & 3) * 8192;
    bf16x8 av[8], bv[4];
#pragma unroll
    for (int f = 0; f < 8; ++f) av[f] = *(const bf16x8*)&pA[abase + f * 512];
#pragma unroll
    for (int g = 0; g < 4; ++g) bv[g] = *(const bf16x8*)&pB[bbase + g * 512];
    if (t + 2 < nkt) { stA(t + 2); stB(t + 2); }
    asm volatile("s_waitcnt lgkmcnt(0)" ::: "memory");
    SB();
    __builtin_amdgcn_s_setprio(1);
#pragma unroll
    for (int f = 0; f < 8; ++f)
#pragma unroll
      for (int g = 0; g < 4; ++g)
        acc[f][g] = MFMA16(av[f], bv[g], acc[f][g]);
    __builtin_amdgcn_s_setprio(0);
    if (t + 2 < nkt)      asm volatile("s_waitcnt vmcnt(4)" ::: "memory");
    else if (t + 1 < nkt) asm volatile("s_waitcnt vmcnt(0)" ::: "memory");
  }

  const int jj = lane & 15;
  const int rb = m0 + wm * 128 + ((lane >> 4) << 2);
  const int q = (n0 >> 6) + wn;
#pragma unroll
  for (int f = 0; f < 8; ++f)
#pragma unroll
    for (int r = 0; r < 4; ++r) {
      u16x4 pk;
      pk[0] = f2bfbits(acc[f][0][r]);
      pk[1] = f2bfbits(acc[f][1][r]);
      pk[2] = f2bfbits(acc[f][2][r]);
      pk[3] = f2bfbits(acc[f][3][r]);
      *(u16x4*)&Cb[(size_t)(rb + f * 16 + r) * 4096 + q * 64 + jj * 4] = pk;
    }
}

// ---------------------------------------------------------------------------
// Decoder-step GEMM+cell body (r10 gemm8 MODE 1, lda=K=ldh=1536) — device fn
// used inside the persistent cooperative loop.
// ---------------------------------------------------------------------------
__device__ __forceinline__ void dec_step_body(
    char* smem_raw, const bf16* __restrict__ Sc, const bf16* __restrict__ Wd,
    const bf16* __restrict__ E, const float* __restrict__ bias,
    bf16* __restrict__ cst, bf16* __restrict__ hout) {
  bf16* lsA = (bf16*)smem_raw;
  bf16* lsB = lsA + 4 * 8192;

  const int tid = threadIdx.x;
  const int lane = tid & 63;
  const int wave = tid >> 6;
  const int wm = wave >> 2, wn = wave & 3;

  const int bid = blockIdx.x;
  const int wgid = (bid & 7) * 32 + (bid >> 3);
  const int m0 = (wgid & 15) * 256, n0 = (wgid >> 4) * 256;  // n-major

  constexpr int K = 1536, lda = 1536, ldh = 1536;
  constexpr int nkt = K >> 5;

  const int srow = tid >> 2;
  const int scol = ((tid & 3) ^ ((srow >> 1) & 3)) * 8;
  const bf16* gAs = Sc + (size_t)(m0 + srow) * lda + scol;
  const bf16* gBs = Wd + (size_t)(n0 + srow) * K + scol;

  auto stA = [&](int kt) {
    bf16* d = lsA + (kt & 3) * 8192 + tid * 8;
    const bf16* s = gAs + (size_t)kt * 32;
    gload_lds16(s, d);
    gload_lds16(s + (size_t)128 * lda, d + 4096);
  };
  auto stB = [&](int kt) {
    bf16* d = lsB + (kt & 3) * 8192 + tid * 8;
    const bf16* s = gBs + (size_t)kt * 32;
    gload_lds16(s, d);
    gload_lds16(s + (size_t)128 * K, d + 4096);
  };

  const int sw = ((lane & 15) >> 1) & 3;
  const int rslot = ((lane >> 4) ^ sw) * 8;
  const int abase = (wm * 128 + (lane & 15)) * 32 + rslot;
  const int bbase = (wn * 64 + (lane & 15)) * 32 + rslot;

  f32x4 acc[8][4] = {};

  stA(0); stB(0); stA(1); stB(1);
  asm volatile("s_waitcnt vmcnt(4)" ::: "memory");

  for (int t = 0; t < nkt; ++t) {
    SB();
    __builtin_amdgcn_s_barrier();
    SB();
    const bf16* pA = lsA + (t & 3) * 8192;
    const bf16* pB = lsB + (t & 3) * 8192;
    bf16x8 av[8], bv[4];
#pragma unroll
    for (int f = 0; f < 8; ++f) av[f] = *(const bf16x8*)&pA[abase + f * 512];
#pragma unroll
    for (int g = 0; g < 4; ++g) bv[g] = *(const bf16x8*)&pB[bbase + g * 512];
    if (t + 2 < nkt) { stA(t + 2); stB(t + 2); }
    asm volatile("s_waitcnt lgkmcnt(0)" ::: "memory");
    SB();
    __builtin_amdgcn_s_setprio(1);
#pragma unroll
    for (int f = 0; f < 8; ++f)
#pragma unroll
      for (int g = 0; g < 4; ++g)
        acc[f][g] = MFMA16(av[f], bv[g], acc[f][g]);
    __builtin_amdgcn_s_setprio(0);
    if (t + 2 < nkt)      asm volatile("s_waitcnt vmcnt(4)" ::: "memory");
    else if (t + 1 < nkt) asm volatile("s_waitcnt vmcnt(0)" ::: "memory");
  }

  const int jj = lane & 15;
  const int rb = m0 + wm * 128 + ((lane >> 4) << 2);
  const int q = (n0 >> 6) + wn;
  const int j = q * 16 + jj;
  const f32x4 bq = *(const f32x4*)&bias[q * 64 + jj * 4];
#pragma unroll
  for (int f = 0; f < 8; ++f) {
#pragma unroll
    for (int r = 0; r < 4; ++r) {
      const int row = rb + f * 16 + r;
      const u16x4 xv = __builtin_nontemporal_load(
          (const u16x4*)&E[(size_t)row * 4096 + q * 64 + jj * 4]);
      const float gi = acc[f][0][r] + bf2f(xv[0]) + bq[0];
      const float gf = acc[f][1][r] + bf2f(xv[1]) + bq[1];
      const float gg = acc[f][2][r] + bf2f(xv[2]) + bq[2];
      const float go = acc[f][3][r] + bf2f(xv[3]) + bq[3];
      const size_t ci = (size_t)row * 1024 + j;
      const float cold = bf2f(((const unsigned short*)cst)[ci]);
      const float cn = sigmoidf_(gf) * cold + sigmoidf_(gi) * tanhf(gg);
      cst[ci] = (bf16)cn;
      hout[(size_t)row * ldh + j] = (bf16)(sigmoidf_(go) * tanhf(cn));
    }
  }
}

// ---------------------------------------------------------------------------
// Out-projection body (gemm_bt<128,64,...,MODE1> adapted to 512 threads,
// 8 waves = 4m x 2n, wave tile 32x32). XCD m-grouping. Device fn for the loop.
// ---------------------------------------------------------------------------
__device__ __forceinline__ void outproj_body(
    char* smem_raw, const bf16* __restrict__ A, const bf16* __restrict__ Bw,
    const float* __restrict__ outb, float* __restrict__ dout,
    bf16* __restrict__ anote, int nstep) {
  constexpr int BM = 128, BN = 64, BK = 64;
  constexpr int SM = 32, SN = 32, FM = 2, FN = 2;
  constexpr int lda = 1536, ldb = 1024, K = 1024;
  bf16* lsA = (bf16*)smem_raw;       // 128*64
  bf16* lsB = lsA + BM * BK;         // 64*64

  const int tid = threadIdx.x;
  const int lane = tid & 63;
  const int wave = tid >> 6;
  const int wm = wave >> 1, wn = wave & 1;

  const int bid = blockIdx.x;                 // 0..255
  const int mi = (bid & 7) * 4 + ((bid >> 3) & 3);
  const int ni = bid >> 5;
  const int m0 = mi * BM, n0 = ni * BN;

  f32x4 acc[FM][FN] = {};

  const bf16* gA = A + (size_t)m0 * lda;
  const bf16* gB = Bw + (size_t)n0 * ldb;

  for (int k0 = 0; k0 < K; k0 += BK) {
#pragma unroll
    for (int i = 0; i < 2; ++i) {             // (BM*8)/512
      int idx = i * 512 + tid;
      gload_lds16(gA + (size_t)(idx >> 3) * lda + k0 + (idx & 7) * 8, &lsA[idx * 8]);
    }
    gload_lds16(gB + (size_t)(tid >> 3) * ldb + k0 + (tid & 7) * 8, &lsB[tid * 8]);
    __syncthreads();

#pragma unroll
    for (int kk = 0; kk < BK; kk += 32) {
      bf16x8 av[FM], bv[FN];
#pragma unroll
      for (int i = 0; i < FM; ++i)
        av[i] = *(const bf16x8*)&lsA[(wm * SM + i * 16 + (lane & 15)) * BK + kk + (lane >> 4) * 8];
#pragma unroll
      for (int jf = 0; jf < FN; ++jf)
        bv[jf] = *(const bf16x8*)&lsB[(wn * SN + jf * 16 + (lane & 15)) * BK + kk + (lane >> 4) * 8];
#pragma unroll
      for (int i = 0; i < FM; ++i)
#pragma unroll
        for (int jf = 0; jf < FN; ++jf)
          acc[i][jf] = MFMA16(av[i], bv[jf], acc[i][jf]);
    }
    __syncthreads();
  }

#pragma unroll
  for (int i = 0; i < FM; ++i) {
#pragma unroll
    for (int jf = 0; jf < FN; ++jf) {
      const int col = n0 + wn * SN + jf * 16 + (lane & 15);
      const int rbase = m0 + wm * SM + i * 16 + ((lane >> 4) << 2);
#pragma unroll
      for (int r = 0; r < 4; ++r) {
        const int row = rbase + r;
        float v = sigmoidf_(acc[i][jf][r] + outb[col]);
        const int l = row >> 8, b = row & 255;
        dout[((size_t)(b * 256 + l * 16 + nstep)) * 512 + col] = v;
        anote[(size_t)row * 1536 + col] = (bf16)v;
      }
    }
  }
}

// ---------------------------------------------------------------------------
// Persistent cooperative decoder loop: 16 x { step GEMM+cell ; sync ;
// out-projection ; sync } in ONE launch. 256 blocks x 512 threads.
// ---------------------------------------------------------------------------
__global__ __launch_bounds__(512, 2)
void dec_loop(const bf16* __restrict__ Wd, const bf16* __restrict__ E,
              const float* __restrict__ bdP, bf16* __restrict__ cdec,
              bf16* __restrict__ Ab0, bf16* __restrict__ Ab1,
              const bf16* __restrict__ Wo, const float* __restrict__ outb,
              float* __restrict__ out) {
  extern __shared__ __align__(16) char smem_raw[];
  cg::grid_group grid = cg::this_grid();
  for (int n = 0; n < 16; ++n) {
    bf16* Sc = (n & 1) ? Ab1 : Ab0;
    bf16* Sn = (n & 1) ? Ab0 : Ab1;
    dec_step_body(smem_raw, Sc, Wd, E, bdP, cdec, Sn + 512);
    grid.sync();
    outproj_body(smem_raw, Sn + 512, Wo, outb, out, Sn, n);
    grid.sync();
  }
}

// ---------------------------------------------------------------------------
// Persistent cooperative conductor chain: 16 levels in ONE launch.
// Body = gemm_cell<32,2,2,2> (256 threads), XCD qb-grouping.
// ---------------------------------------------------------------------------
__device__ __forceinline__ void cond_cell_body(
    const bf16* __restrict__ A, const bf16* __restrict__ Bw,
    const bf16* __restrict__ X, const float* __restrict__ bias,
    float* __restrict__ cst, bf16* __restrict__ hout) {
  constexpr int BK = 64, K = 1024;
  __shared__ __align__(16) bf16 lsA[32 * BK];
  __shared__ __align__(16) bf16 lsB[128 * BK];

  const int tid = threadIdx.x;
  const int lane = tid & 63;
  const int wave = tid >> 6;
  const int wm = wave >> 1, wj = wave & 1;

  const int flat = blockIdx.x;                // 0..255
  const int qbi = (flat & 7) * 4 + ((flat >> 3) & 3);
  const int mi = flat >> 5;
  const int m0 = mi * 32;
  const int qb = qbi * 2;

  f32x4 acc[1][4] = {};

  const bf16* gA = A + (size_t)m0 * 1024;
  const bf16* gB = Bw + (size_t)(qb * 64) * K;

  for (int k0 = 0; k0 < K; k0 += BK) {
    {
      int idx = tid;  // (32*8)/256 = 1
      gload_lds16(gA + (size_t)(idx >> 3) * 1024 + k0 + (idx & 7) * 8, &lsA[idx * 8]);
    }
#pragma unroll
    for (int i = 0; i < 4; ++i) {  // (128*8)/256
      int idx = i * 256 + tid;
      gload_lds16(gB + (size_t)(idx >> 3) * K + k0 + (idx & 7) * 8, &lsB[idx * 8]);
    }
    __syncthreads();

#pragma unroll
    for (int kk = 0; kk < BK; kk += 32) {
      bf16x8 av = *(const bf16x8*)&lsA[(wm * 16 + (lane & 15)) * BK + kk + (lane >> 4) * 8];
#pragma unroll
      for (int g = 0; g < 4; ++g) {
        bf16x8 bv = *(const bf16x8*)
            &lsB[((wj * 1) * 64 + g * 16 + (lane & 15)) * BK + kk + (lane >> 4) * 8];
        acc[0][g] = MFMA16(av, bv, acc[0][g]);
      }
    }
    __syncthreads();
  }

  const int q = qb + wj;
  const int jj = lane & 15;
  const int j = q * 16 + jj;
  const int rbase = m0 + wm * 16 + ((lane >> 4) << 2);
  const f32x4 bq = *(const f32x4*)&bias[q * 64 + jj * 4];
#pragma unroll
  for (int r = 0; r < 4; ++r) {
    const int row = rbase + r;
    const u16x4 xv = *(const u16x4*)&X[(size_t)row * 4096 + q * 64 + jj * 4];
    const float gi = acc[0][0][r] + bf2f(xv[0]) + bq[0];
    const float gf = acc[0][1][r] + bf2f(xv[1]) + bq[1];
    const float gg = acc[0][2][r] + bf2f(xv[2]) + bq[2];
    const float go = acc[0][3][r] + bf2f(xv[3]) + bq[3];
    const size_t ci = (size_t)row * 1024 + j;
    const float c = sigmoidf_(gf) * cst[ci] + sigmoidf_(gi) * tanhf(gg);
    cst[ci] = c;
    hout[(size_t)row * 1024 + j] = (bf16)(sigmoidf_(go) * tanhf(c));
  }
}

__global__ __launch_bounds__(256, 2)
void cond_chain(const bf16* __restrict__ hz0, const bf16* __restrict__ Wchh,
                const bf16* __restrict__ Xz, const float* __restrict__ bias,
                float* __restrict__ cc, bf16* __restrict__ emb) {
  cg::grid_group grid = cg::this_grid();
  for (int l = 0; l < 16; ++l) {
    const bf16* A = (l == 0) ? hz0 : emb + (size_t)(l - 1) * 262144;
    cond_cell_body(A, Wchh, Xz + (size_t)l * 1048576, bias, cc,
                   emb + (size_t)l * 262144);
    grid.sync();
  }
}

// ---------------- packing / init kernels (vectorized, 4 elem/thread) -------

__device__ __forceinline__ u16x4 f4_to_bf4(f32x4 v) {
  u16x4 o;
  o[0] = f2bfbits(v[0]); o[1] = f2bfbits(v[1]);
  o[2] = f2bfbits(v[2]); o[3] = f2bfbits(v[3]);
  return o;
}

__device__ __forceinline__ int p_src_row(int n) {
  int q = n >> 6, gate = (n >> 4) & 3, jj = n & 15;
  return gate * 1024 + q * 16 + jj;
}

__global__ void conv_f32_bf16_4(const float* __restrict__ src, bf16* __restrict__ dst) {
  int idx = (blockIdx.x * 256 + threadIdx.x) * 4;
  *(u16x4*)&dst[idx] = f4_to_bf4(*(const f32x4*)&src[idx]);
}

__global__ void pack_w_dec(const float* __restrict__ wih, const float* __restrict__ whh,
                           bf16* __restrict__ dst) {
  int idx = (blockIdx.x * 256 + threadIdx.x) * 4;
  int n = idx / 1536, c = idx - n * 1536;
  int r = p_src_row(n);
  const float* s = (c < 512) ? &wih[(size_t)r * 1536 + 1024 + c]
                             : &whh[(size_t)r * 1024 + (c - 512)];
  *(u16x4*)&dst[idx] = f4_to_bf4(*(const f32x4*)s);
}

__global__ void pack_w_emb(const float* __restrict__ wih, bf16* __restrict__ dst) {
  int idx = (blockIdx.x * 256 + threadIdx.x) * 4;
  int n = idx >> 10, c = idx & 1023;
  *(u16x4*)&dst[idx] = f4_to_bf4(*(const f32x4*)&wih[(size_t)p_src_row(n) * 1536 + c]);
}

__global__ void pack_w_perm(const float* __restrict__ src, bf16* __restrict__ dst, int Kw) {
  int idx = (blockIdx.x * 256 + threadIdx.x) * 4;
  int n = idx / Kw, c = idx - n * Kw;
  *(u16x4*)&dst[idx] = f4_to_bf4(*(const f32x4*)&src[(size_t)p_src_row(n) * Kw + c]);
}

__global__ void pack_bias2(const float* __restrict__ dbih, const float* __restrict__ dbhh,
                           float* __restrict__ ddst,
                           const float* __restrict__ cbih, const float* __restrict__ cbhh,
                           float* __restrict__ cdst) {
  int n = blockIdx.x * 256 + threadIdx.x;
  int q = n >> 6, jj = (n >> 2) & 15, g = n & 3;
  int r = g * 1024 + q * 16 + jj;
  ddst[n] = dbih[r] + dbhh[r];
  cdst[n] = cbih[r] + cbhh[r];
}

__global__ void pack_zb(const float* __restrict__ z, bf16* __restrict__ dst) {
  int idx = (blockIdx.x * 256 + threadIdx.x) * 4;
  int m = idx >> 9, k = idx & 511;
  int l = m >> 8, b = m & 255;
  *(u16x4*)&dst[idx] =
      f4_to_bf4(*(const f32x4*)&z[((size_t)b * 256 + 16 * l) * 512 + k]);
}

__global__ void init_cond(float* __restrict__ cc, bf16* __restrict__ hz0) {
  int idx = (blockIdx.x * 256 + threadIdx.x) * 4;
  *(f32x4*)&cc[idx] = f32x4{0.f, 0.f, 0.f, 0.f};
  *(u16x4*)&hz0[idx] = u16x4{0, 0, 0, 0};
}

__global__ void init_state(const float* __restrict__ h0, const float* __restrict__ c0,
                           bf16* __restrict__ Abuf, bf16* __restrict__ cdec) {
  int idx = (blockIdx.x * 256 + threadIdx.x) * 4;
  int m = idx / 1536, c = idx - m * 1536;
  if (c < 512) {
    *(u16x4*)&Abuf[idx] = u16x4{0, 0, 0, 0};
  } else {
    int j = c - 512;
    size_t s = (size_t)m * 1024 + j;
    *(u16x4*)&Abuf[idx] = f4_to_bf4(*(const f32x4*)&h0[s]);
    *(u16x4*)&cdec[s] = f4_to_bf4(*(const f32x4*)&c0[s]);
  }
}

extern "C" void kernel_launch(void* const* d_in, const int* in_sizes, int n_in,
                              void* d_out, int out_size, void* d_ws, size_t ws_size,
                              hipStream_t stream) {
  const float* z        = (const float*)d_in[0];
  const float* dec_h0   = (const float*)d_in[1];
  const float* dec_c0   = (const float*)d_in[2];
  const float* cond_Wih = (const float*)d_in[5];
  const float* cond_Whh = (const float*)d_in[6];
  const float* cond_bih = (const float*)d_in[7];
  const float* cond_bhh = (const float*)d_in[8];
  const float* dec_Wih  = (const float*)d_in[9];
  const float* dec_Whh  = (const float*)d_in[10];
  const float* dec_bih  = (const float*)d_in[11];
  const float* dec_bhh  = (const float*)d_in[12];
  const float* out_W    = (const float*)d_in[13];
  const float* out_b    = (const float*)d_in[14];
  float* out = (float*)d_out;

  char* ws = (char*)d_ws;
  size_t off = 0;
  auto alloc = [&](size_t bytes) {
    void* p = ws + off;
    off += (bytes + 255) & ~(size_t)255;
    return p;
  };
  bf16* E     = (bf16*)alloc(4096ull * 4096 * 2);
  bf16* Xz    = (bf16*)alloc(4096ull * 4096 * 2);
  bf16* cdec  = (bf16*)alloc(4096ull * 1024 * 2);
  bf16* Ab0   = (bf16*)alloc(4096ull * 1536 * 2);
  bf16* Ab1   = (bf16*)alloc(4096ull * 1536 * 2);
  bf16* Wd    = (bf16*)alloc(4096ull * 1536 * 2);
  bf16* We    = (bf16*)alloc(4096ull * 1024 * 2);
  bf16* Wcih  = (bf16*)alloc(4096ull * 512 * 2);
  bf16* Wchh  = (bf16*)alloc(4096ull * 1024 * 2);
  bf16* Wo    = (bf16*)alloc(512ull * 1024 * 2);
  float* cc   = (float*)alloc(256ull * 1024 * 4);
  bf16* emb   = (bf16*)alloc(4096ull * 1024 * 2);
  bf16* Zb    = (bf16*)alloc(4096ull * 512 * 2);
  bf16* hz0   = (bf16*)alloc(256ull * 1024 * 2);
  float* bdP  = (float*)alloc(4096ull * 4);
  float* bcP  = (float*)alloc(4096ull * 4);

  dim3 b256(256);

  hipFuncSetAttribute(reinterpret_cast<const void*>(&gemm8<0>),
                      hipFuncAttributeMaxDynamicSharedMemorySize, 131072);
  hipFuncSetAttribute(reinterpret_cast<const void*>(&dec_loop),
                      hipFuncAttributeMaxDynamicSharedMemorySize, 131072);

  // packing (vectorized)
  pack_w_perm<<<4096 * 512 / 1024, b256, 0, stream>>>(cond_Wih, Wcih, 512);
  pack_w_perm<<<4096 * 1024 / 1024, b256, 0, stream>>>(cond_Whh, Wchh, 1024);
  conv_f32_bf16_4<<<512 * 1024 / 1024, b256, 0, stream>>>(out_W, Wo);
  pack_w_dec<<<4096 * 1536 / 1024, b256, 0, stream>>>(dec_Wih, dec_Whh, Wd);
  pack_w_emb<<<4096 * 1024 / 1024, b256, 0, stream>>>(dec_Wih, We);
  pack_bias2<<<16, b256, 0, stream>>>(dec_bih, dec_bhh, bdP, cond_bih, cond_bhh, bcP);
  pack_zb<<<4096 * 512 / 1024, b256, 0, stream>>>(z, Zb);
  init_cond<<<256 * 1024 / 1024, b256, 0, stream>>>(cc, hz0);
  init_state<<<4096 * 1536 / 1024, b256, 0, stream>>>(dec_h0, dec_c0, Ab0, cdec);

  // Xz = Zb @ Wcih^T (X layout)
  gemm8<0><<<256, 512, 131072, stream>>>(Zb, 512, Wcih, 512, Xz);

  // conductor chain: ONE cooperative launch, 16 levels
  {
    void* args[] = {(void*)&hz0, (void*)&Wchh, (void*)&Xz, (void*)&bcP,
                    (void*)&cc, (void*)&emb};
    hipLaunchCooperativeKernel(reinterpret_cast<void*>(&cond_chain),
                               dim3(256), dim3(256), args, 0, stream);
  }

  // E = emb @ We^T (X layout)
  gemm8<0><<<256, 512, 131072, stream>>>(emb, 1024, We, 1024, E);

  // decoder loop: ONE cooperative launch, 16 steps (GEMM+cell ; outproj)
  {
    void* args[] = {(void*)&Wd, (void*)&E, (void*)&bdP, (void*)&cdec,
                    (void*)&Ab0, (void*)&Ab1, (void*)&Wo, (void*)&out_b,
                    (void*)&out};
    hipLaunchCooperativeKernel(reinterpret_cast<void*>(&dec_loop),
                               dim3(256), dim3(512), args, 131072, stream);
  }
}

// Round 14
// 1692.375 us; speedup vs baseline: 2.1426x; 2.1426x over previous
//
#include <hip/hip_runtime.h>

typedef __bf16 bf16;
typedef __attribute__((ext_vector_type(8))) __bf16 bf16x8;
typedef __attribute__((ext_vector_type(4))) float f32x4;
typedef __attribute__((ext_vector_type(4))) unsigned short u16x4;

__device__ __forceinline__ void gload_lds16(const void* g, void* l) {
  __builtin_amdgcn_global_load_lds(
      (const __attribute__((address_space(1))) void*)g,
      (__attribute__((address_space(3))) void*)l, 16, 0, 0);
}

__device__ __forceinline__ float sigmoidf_(float x) { return 1.0f / (1.0f + expf(-x)); }

__device__ __forceinline__ float bf2f(unsigned short u) {
  union { unsigned int i; float f; } v;
  v.i = ((unsigned int)u) << 16;
  return v.f;
}
__device__ __forceinline__ unsigned short f2bfbits(float x) {
  union { bf16 b; unsigned short u; } v;
  v.b = (bf16)x;
  return v.u;
}

#define SB() __builtin_amdgcn_sched_barrier(0)
#define MFMA16(a, b, c) __builtin_amdgcn_mfma_f32_16x16x32_bf16(a, b, c, 0, 0, 0)

// ---------------------------------------------------------------------------
// 256x256-tile GEMM, BK=32, ring-4 LDS slots, ONE barrier per K-tile.
// (Best-measured r10 configuration: bf16 c-state, n-major XCD grouping for
// B-panel L2 residency.)
// A [M x K] bf16 (lda); Bw [4096 x K] bf16, P-packed rows
//   (n' = q*64 + gate*16 + jj, source row = gate*1024 + q*16 + jj).
// MODE 0: pack 4 gates -> u16x4 bf16 store, X layout (q*64 + jj*4 + g).
// MODE 1: fused LSTM cell; X (bf16)/bias (f32) X-layout; cst is bf16.
// ---------------------------------------------------------------------------
template<int MODE>
__global__ __launch_bounds__(512, 2)
void gemm8(const bf16* __restrict__ A, int lda,
           const bf16* __restrict__ Bw, int K,
           bf16* __restrict__ Cb,
           const bf16* __restrict__ X, const float* __restrict__ bias,
           bf16* __restrict__ cst, bf16* __restrict__ hout, int ldh) {
  extern __shared__ __align__(16) char smem_raw[];
  bf16* lsA = (bf16*)smem_raw;    // [4][256][32]
  bf16* lsB = lsA + 4 * 8192;     // [4][256][32]

  const int tid = threadIdx.x;
  const int lane = tid & 63;
  const int wave = tid >> 6;
  const int wm = wave >> 2, wn = wave & 3;

  const int bid = blockIdx.x;
  const int wgid = (bid & 7) * 32 + (bid >> 3);  // XCD-bijective (256 wgs)
  // n-major grouping: each XCD owns 2 n-panels (B slice 1.5MB -> L2-resident)
  const int m0 = (wgid & 15) * 256, n0 = (wgid >> 4) * 256;

  const int nkt = K >> 5;  // BK=32

  // staging: dest linear in tid (row = tid>>2, slot = tid&3);
  // source col pre-unswizzled: scol = (slot ^ ((row>>1)&3)) * 8
  const int srow = tid >> 2;  // 0..127
  const int scol = ((tid & 3) ^ ((srow >> 1) & 3)) * 8;
  const bf16* gAs = A + (size_t)(m0 + srow) * lda + scol;
  const bf16* gBs = Bw + (size_t)(n0 + srow) * K + scol;

  auto stA = [&](int kt) {
    bf16* d = lsA + (kt & 3) * 8192 + tid * 8;
    const bf16* s = gAs + (size_t)kt * 32;
    gload_lds16(s, d);
    gload_lds16(s + (size_t)128 * lda, d + 4096);
  };
  auto stB = [&](int kt) {
    bf16* d = lsB + (kt & 3) * 8192 + tid * 8;
    const bf16* s = gBs + (size_t)kt * 32;
    gload_lds16(s, d);
    gload_lds16(s + (size_t)128 * K, d + 4096);
  };

  // ds_read: logical slot = lane>>4, phys = logical ^ ((row>>1)&3), row=lane&15
  const int sw = ((lane & 15) >> 1) & 3;
  const int rslot = ((lane >> 4) ^ sw) * 8;
  const int abase = (wm * 128 + (lane & 15)) * 32 + rslot;  // + f*512
  const int bbase = (wn * 64 + (lane & 15)) * 32 + rslot;   // + g*512

  f32x4 acc[8][4] = {};

  // prologue: stage tiles 0,1; wait tile 0 (leave tile 1 in flight)
  stA(0); stB(0); stA(1); stB(1);
  asm volatile("s_waitcnt vmcnt(4)" ::: "memory");

  for (int t = 0; t < nkt; ++t) {
    SB();
    __builtin_amdgcn_s_barrier();
    SB();
    const bf16* pA = lsA + (t & 3) * 8192;
    const bf16* pB = lsB + (t & 3) * 8192;
    bf16x8 av[8], bv[4];
#pragma unroll
    for (int f = 0; f < 8; ++f) av[f] = *(const bf16x8*)&pA[abase + f * 512];
#pragma unroll
    for (int g = 0; g < 4; ++g) bv[g] = *(const bf16x8*)&pB[bbase + g * 512];
    if (t + 2 < nkt) { stA(t + 2); stB(t + 2); }
    asm volatile("s_waitcnt lgkmcnt(0)" ::: "memory");
    SB();
    __builtin_amdgcn_s_setprio(1);
#pragma unroll
    for (int f = 0; f < 8; ++f)
#pragma unroll
      for (int g = 0; g < 4; ++g)
        acc[f][g] = MFMA16(av[f], bv[g], acc[f][g]);
    __builtin_amdgcn_s_setprio(0);
    if (t + 2 < nkt)      asm volatile("s_waitcnt vmcnt(4)" ::: "memory");
    else if (t + 1 < nkt) asm volatile("s_waitcnt vmcnt(0)" ::: "memory");
  }

  // ---------------- epilogue ----------------
  const int jj = lane & 15;
  const int rb = m0 + wm * 128 + ((lane >> 4) << 2);
  const int q = (n0 >> 6) + wn;  // j16 group (wave-uniform)
  if constexpr (MODE == 0) {
#pragma unroll
    for (int f = 0; f < 8; ++f)
#pragma unroll
      for (int r = 0; r < 4; ++r) {
        u16x4 pk;
        pk[0] = f2bfbits(acc[f][0][r]);
        pk[1] = f2bfbits(acc[f][1][r]);
        pk[2] = f2bfbits(acc[f][2][r]);
        pk[3] = f2bfbits(acc[f][3][r]);
        *(u16x4*)&Cb[(size_t)(rb + f * 16 + r) * 4096 + q * 64 + jj * 4] = pk;
      }
  } else {
    const int j = q * 16 + jj;
    const f32x4 bq = *(const f32x4*)&bias[q * 64 + jj * 4];
#pragma unroll
    for (int f = 0; f < 8; ++f) {
#pragma unroll
      for (int r = 0; r < 4; ++r) {
        const int row = rb + f * 16 + r;
        const u16x4 xv = *(const u16x4*)&X[(size_t)row * 4096 + q * 64 + jj * 4];
        const float gi = acc[f][0][r] + bf2f(xv[0]) + bq[0];
        const float gf = acc[f][1][r] + bf2f(xv[1]) + bq[1];
        const float gg = acc[f][2][r] + bf2f(xv[2]) + bq[2];
        const float go = acc[f][3][r] + bf2f(xv[3]) + bq[3];
        const size_t ci = (size_t)row * 1024 + j;
        const float cold = bf2f(((const unsigned short*)cst)[ci]);
        const float cn = sigmoidf_(gf) * cold + sigmoidf_(gi) * tanhf(gg);
        cst[ci] = (bf16)cn;
        hout[(size_t)row * ldh + j] = (bf16)(sigmoidf_(go) * tanhf(cn));
      }
    }
  }
}

// ---------------------------------------------------------------------------
// 2-phase GEMM for the out-projection (N=512).
// MODE 1: sigmoid + scatter to notes + bf16 note feedback; XCD m-grouped.
// ---------------------------------------------------------------------------
template<int BM, int BN, int WM, int WN, int MODE>
__global__ __launch_bounds__(WM * WN * 64)
void gemm_bt(const bf16* __restrict__ A, int lda,
             const bf16* __restrict__ Bw, int ldb,
             float* __restrict__ C, int ldc, int K,
             const float* __restrict__ outb, float* __restrict__ dout,
             bf16* __restrict__ anote, int nstep) {
  constexpr int BK = 64;
  constexpr int THREADS = WM * WN * 64;
  constexpr int SM = BM / WM, SN = BN / WN;
  constexpr int FM = SM / 16, FN = SN / 16;

  __shared__ __align__(16) bf16 lsA[BM * BK];
  __shared__ __align__(16) bf16 lsB[BN * BK];

  const int tid = threadIdx.x;
  const int lane = tid & 63;
  const int wave = tid >> 6;
  const int wm = wave / WN, wn = wave % WN;

  int mi = blockIdx.y, ni = blockIdx.x;
  if constexpr (MODE == 1) {
    // grid (8,32): XCD-local m-grouping (4 A-panels + Wo per XCD -> L2-fit)
    const int flat = blockIdx.y * 8 + blockIdx.x;
    mi = (flat & 7) * 4 + ((flat >> 3) & 3);
    ni = flat >> 5;
  }
  const int m0 = mi * BM;
  const int n0 = ni * BN;

  f32x4 acc[FM][FN] = {};

  const bf16* gA = A + (size_t)m0 * lda;
  const bf16* gB = Bw + (size_t)n0 * ldb;

  for (int k0 = 0; k0 < K; k0 += BK) {
#pragma unroll
    for (int i = 0; i < (BM * 8) / THREADS; ++i) {
      int idx = i * THREADS + tid;
      gload_lds16(gA + (size_t)(idx >> 3) * lda + k0 + (idx & 7) * 8, &lsA[idx * 8]);
    }
#pragma unroll
    for (int i = 0; i < (BN * 8) / THREADS; ++i) {
      int idx = i * THREADS + tid;
      gload_lds16(gB + (size_t)(idx >> 3) * ldb + k0 + (idx & 7) * 8, &lsB[idx * 8]);
    }
    __syncthreads();

#pragma unroll
    for (int kk = 0; kk < BK; kk += 32) {
      bf16x8 av[FM], bv[FN];
#pragma unroll
      for (int i = 0; i < FM; ++i)
        av[i] = *(const bf16x8*)&lsA[(wm * SM + i * 16 + (lane & 15)) * BK + kk + (lane >> 4) * 8];
#pragma unroll
      for (int j = 0; j < FN; ++j)
        bv[j] = *(const bf16x8*)&lsB[(wn * SN + j * 16 + (lane & 15)) * BK + kk + (lane >> 4) * 8];
#pragma unroll
      for (int i = 0; i < FM; ++i)
#pragma unroll
        for (int j = 0; j < FN; ++j)
          acc[i][j] = MFMA16(av[i], bv[j], acc[i][j]);
    }
    __syncthreads();
  }

#pragma unroll
  for (int i = 0; i < FM; ++i) {
#pragma unroll
    for (int j = 0; j < FN; ++j) {
      const int col = n0 + wn * SN + j * 16 + (lane & 15);
      const int rbase = m0 + wm * SM + i * 16 + ((lane >> 4) << 2);
#pragma unroll
      for (int r = 0; r < 4; ++r) {
        const int row = rbase + r;
        float v = acc[i][j][r];
        if constexpr (MODE == 0) {
          C[(size_t)row * ldc + col] = v;
        } else {
          v = sigmoidf_(v + outb[col]);
          const int l = row >> 8, b = row & 255;
          dout[((size_t)(b * 256 + l * 16 + nstep)) * 512 + col] = v;
          anote[(size_t)row * 1536 + col] = (bf16)v;
        }
      }
    }
  }
}

// ---------------------------------------------------------------------------
// Small fused GEMM+cell for the conductor chain (M=256), P layout.
// XCD-local qb-grouping (Wchh col-panels L2-resident).
// ---------------------------------------------------------------------------
template<int BM, int BJ, int WM, int WJ>
__global__ __launch_bounds__(WM * WJ * 64, 2)
void gemm_cell(const bf16* __restrict__ A, int lda,
               const bf16* __restrict__ Bw,
               const bf16* __restrict__ X,
               const float* __restrict__ bias,
               float* __restrict__ cst,
               bf16* __restrict__ hout, int ldh, int K) {
  constexpr int BK = 64;
  constexpr int THREADS = WM * WJ * 64;
  constexpr int BN = BJ * 64;
  constexpr int SM = BM / WM;
  constexpr int TJ = BJ / WJ;
  constexpr int FM = SM / 16;

  __shared__ __align__(16) bf16 lsA[BM * BK];
  __shared__ __align__(16) bf16 lsB[BN * BK];

  const int tid = threadIdx.x;
  const int lane = tid & 63;
  const int wave = tid >> 6;
  const int wm = wave / WJ, wj = wave % WJ;

  int qbi = blockIdx.x, mi = blockIdx.y;
  if constexpr (BM == 32 && BJ == 2) {
    // grid (32,8): XCD-local qb-grouping
    const int flat = blockIdx.y * 32 + blockIdx.x;
    qbi = (flat & 7) * 4 + ((flat >> 3) & 3);
    mi = flat >> 5;
  }
  const int m0 = mi * BM;
  const int qb = qbi * BJ;

  f32x4 acc[FM][TJ][4] = {};

  const bf16* gA = A + (size_t)m0 * lda;
  const bf16* gB = Bw + (size_t)(qb * 64) * K;

  for (int k0 = 0; k0 < K; k0 += BK) {
#pragma unroll
    for (int i = 0; i < (BM * 8) / THREADS; ++i) {
      int idx = i * THREADS + tid;
      gload_lds16(gA + (size_t)(idx >> 3) * lda + k0 + (idx & 7) * 8, &lsA[idx * 8]);
    }
#pragma unroll
    for (int i = 0; i < (BN * 8) / THREADS; ++i) {
      int idx = i * THREADS + tid;
      gload_lds16(gB + (size_t)(idx >> 3) * K + k0 + (idx & 7) * 8, &lsB[idx * 8]);
    }
    __syncthreads();

#pragma unroll
    for (int kk = 0; kk < BK; kk += 32) {
      bf16x8 av[FM], bv[TJ][4];
#pragma unroll
      for (int i = 0; i < FM; ++i)
        av[i] = *(const bf16x8*)&lsA[(wm * SM + i * 16 + (lane & 15)) * BK + kk + (lane >> 4) * 8];
#pragma unroll
      for (int t = 0; t < TJ; ++t)
#pragma unroll
        for (int g = 0; g < 4; ++g)
          bv[t][g] = *(const bf16x8*)
              &lsB[((wj * TJ + t) * 64 + g * 16 + (lane & 15)) * BK + kk + (lane >> 4) * 8];
#pragma unroll
      for (int i = 0; i < FM; ++i)
#pragma unroll
        for (int t = 0; t < TJ; ++t)
#pragma unroll
          for (int g = 0; g < 4; ++g)
            acc[i][t][g] = MFMA16(av[i], bv[t][g], acc[i][t][g]);
    }
    __syncthreads();
  }

#pragma unroll
  for (int i = 0; i < FM; ++i) {
#pragma unroll
    for (int t = 0; t < TJ; ++t) {
      const int q = qb + wj * TJ + t;
      const int jj = lane & 15;
      const int j = q * 16 + jj;
      const int rbase = m0 + wm * SM + i * 16 + ((lane >> 4) << 2);
      const f32x4 bq = *(const f32x4*)&bias[q * 64 + jj * 4];
#pragma unroll
      for (int r = 0; r < 4; ++r) {
        const int row = rbase + r;
        const u16x4 xv = *(const u16x4*)&X[(size_t)row * 4096 + q * 64 + jj * 4];
        const float gi = acc[i][t][0][r] + bf2f(xv[0]) + bq[0];
        const float gf = acc[i][t][1][r] + bf2f(xv[1]) + bq[1];
        const float gg = acc[i][t][2][r] + bf2f(xv[2]) + bq[2];
        const float go = acc[i][t][3][r] + bf2f(xv[3]) + bq[3];
        const size_t ci = (size_t)row * 1024 + j;
        const float c = sigmoidf_(gf) * cst[ci] + sigmoidf_(gi) * tanhf(gg);
        cst[ci] = c;
        hout[(size_t)row * ldh + j] = (bf16)(sigmoidf_(go) * tanhf(c));
      }
    }
  }
}

// ---------------- packing / init kernels (vectorized, 4 elem/thread) -------

__device__ __forceinline__ u16x4 f4_to_bf4(f32x4 v) {
  u16x4 o;
  o[0] = f2bfbits(v[0]); o[1] = f2bfbits(v[1]);
  o[2] = f2bfbits(v[2]); o[3] = f2bfbits(v[3]);
  return o;
}

// P row: n' = q*64 + gate*16 + jj  ->  source row gate*1024 + q*16 + jj
__device__ __forceinline__ int p_src_row(int n) {
  int q = n >> 6, gate = (n >> 4) & 3, jj = n & 15;
  return gate * 1024 + q * 16 + jj;
}

__global__ void conv_f32_bf16_4(const float* __restrict__ src, bf16* __restrict__ dst) {
  int idx = (blockIdx.x * 256 + threadIdx.x) * 4;
  *(u16x4*)&dst[idx] = f4_to_bf4(*(const f32x4*)&src[idx]);
}

__global__ void pack_w_dec(const float* __restrict__ wih, const float* __restrict__ whh,
                           bf16* __restrict__ dst) {
  int idx = (blockIdx.x * 256 + threadIdx.x) * 4;  // over 4096*1536
  int n = idx / 1536, c = idx - n * 1536;
  int r = p_src_row(n);
  const float* s = (c < 512) ? &wih[(size_t)r * 1536 + 1024 + c]
                             : &whh[(size_t)r * 1024 + (c - 512)];
  *(u16x4*)&dst[idx] = f4_to_bf4(*(const f32x4*)s);
}

__global__ void pack_w_emb(const float* __restrict__ wih, bf16* __restrict__ dst) {
  int idx = (blockIdx.x * 256 + threadIdx.x) * 4;  // over 4096*1024
  int n = idx >> 10, c = idx & 1023;
  *(u16x4*)&dst[idx] = f4_to_bf4(*(const f32x4*)&wih[(size_t)p_src_row(n) * 1536 + c]);
}

__global__ void pack_w_perm(const float* __restrict__ src, bf16* __restrict__ dst, int Kw) {
  int idx = (blockIdx.x * 256 + threadIdx.x) * 4;  // over 4096*Kw
  int n = idx / Kw, c = idx - n * Kw;
  *(u16x4*)&dst[idx] = f4_to_bf4(*(const f32x4*)&src[(size_t)p_src_row(n) * Kw + c]);
}

// X-layout bias: dst[q*64 + jj*4 + g] = bih[r] + bhh[r]
__global__ void pack_bias(const float* __restrict__ bih, const float* __restrict__ bhh,
                          float* __restrict__ dst) {
  int n = blockIdx.x * 256 + threadIdx.x;  // 4096
  int q = n >> 6, jj = (n >> 2) & 15, g = n & 3;
  int r = g * 1024 + q * 16 + jj;
  dst[n] = bih[r] + bhh[r];
}

__global__ void pack_zb(const float* __restrict__ z, bf16* __restrict__ dst) {
  int idx = (blockIdx.x * 256 + threadIdx.x) * 4;  // over 4096*512
  int m = idx >> 9, k = idx & 511;
  int l = m >> 8, b = m & 255;
  *(u16x4*)&dst[idx] =
      f4_to_bf4(*(const f32x4*)&z[((size_t)b * 256 + 16 * l) * 512 + k]);
}

__global__ void init_cond(float* __restrict__ cc, bf16* __restrict__ hz0) {
  int idx = (blockIdx.x * 256 + threadIdx.x) * 4;  // over 256*1024
  *(f32x4*)&cc[idx] = f32x4{0.f, 0.f, 0.f, 0.f};
  *(u16x4*)&hz0[idx] = u16x4{0, 0, 0, 0};
}

__global__ void init_state(const float* __restrict__ h0, const float* __restrict__ c0,
                           bf16* __restrict__ Abuf, bf16* __restrict__ cdec) {
  int idx = (blockIdx.x * 256 + threadIdx.x) * 4;  // over 4096*1536
  int m = idx / 1536, c = idx - m * 1536;
  if (c < 512) {
    *(u16x4*)&Abuf[idx] = u16x4{0, 0, 0, 0};
  } else {
    int j = c - 512;
    size_t s = (size_t)m * 1024 + j;
    *(u16x4*)&Abuf[idx] = f4_to_bf4(*(const f32x4*)&h0[s]);
    *(u16x4*)&cdec[s] = f4_to_bf4(*(const f32x4*)&c0[s]);
  }
}

extern "C" void kernel_launch(void* const* d_in, const int* in_sizes, int n_in,
                              void* d_out, int out_size, void* d_ws, size_t ws_size,
                              hipStream_t stream) {
  const float* z        = (const float*)d_in[0];
  const float* dec_h0   = (const float*)d_in[1];
  const float* dec_c0   = (const float*)d_in[2];
  const float* cond_Wih = (const float*)d_in[5];
  const float* cond_Whh = (const float*)d_in[6];
  const float* cond_bih = (const float*)d_in[7];
  const float* cond_bhh = (const float*)d_in[8];
  const float* dec_Wih  = (const float*)d_in[9];
  const float* dec_Whh  = (const float*)d_in[10];
  const float* dec_bih  = (const float*)d_in[11];
  const float* dec_bhh  = (const float*)d_in[12];
  const float* out_W    = (const float*)d_in[13];
  const float* out_b    = (const float*)d_in[14];
  float* out = (float*)d_out;

  char* ws = (char*)d_ws;
  size_t off = 0;
  auto alloc = [&](size_t bytes) {
    void* p = ws + off;
    off += (bytes + 255) & ~(size_t)255;
    return p;
  };
  bf16* E     = (bf16*)alloc(4096ull * 4096 * 2);   // emb @ We^T, X layout
  bf16* Xz    = (bf16*)alloc(4096ull * 4096 * 2);   // z @ Wcih^T, X layout
  bf16* cdec  = (bf16*)alloc(4096ull * 1024 * 2);   // decoder c state (bf16)
  bf16* Ab0   = (bf16*)alloc(4096ull * 1536 * 2);   // state ping [note | h]
  bf16* Ab1   = (bf16*)alloc(4096ull * 1536 * 2);   // state pong
  bf16* Wd    = (bf16*)alloc(4096ull * 1536 * 2);   // P [Wih_note | Whh]
  bf16* We    = (bf16*)alloc(4096ull * 1024 * 2);   // P Wih_emb
  bf16* Wcih  = (bf16*)alloc(4096ull * 512 * 2);    // P
  bf16* Wchh  = (bf16*)alloc(4096ull * 1024 * 2);   // P
  bf16* Wo    = (bf16*)alloc(512ull * 1024 * 2);
  float* cc   = (float*)alloc(256ull * 1024 * 4);   // conductor c (f32)
  bf16* emb   = (bf16*)alloc(4096ull * 1024 * 2);
  bf16* Zb    = (bf16*)alloc(4096ull * 512 * 2);
  bf16* hz0   = (bf16*)alloc(256ull * 1024 * 2);
  float* bdP  = (float*)alloc(4096ull * 4);
  float* bcP  = (float*)alloc(4096ull * 4);

  dim3 b256(256);

  hipFuncSetAttribute(reinterpret_cast<const void*>(&gemm8<0>),
                      hipFuncAttributeMaxDynamicSharedMemorySize, 131072);
  hipFuncSetAttribute(reinterpret_cast<const void*>(&gemm8<1>),
                      hipFuncAttributeMaxDynamicSharedMemorySize, 131072);

  // packing (4 elem/thread vectorized)
  pack_w_perm<<<4096 * 512 / 1024, b256, 0, stream>>>(cond_Wih, Wcih, 512);
  pack_w_perm<<<4096 * 1024 / 1024, b256, 0, stream>>>(cond_Whh, Wchh, 1024);
  conv_f32_bf16_4<<<512 * 1024 / 1024, b256, 0, stream>>>(out_W, Wo);
  pack_w_dec<<<4096 * 1536 / 1024, b256, 0, stream>>>(dec_Wih, dec_Whh, Wd);
  pack_w_emb<<<4096 * 1024 / 1024, b256, 0, stream>>>(dec_Wih, We);
  pack_bias<<<16, b256, 0, stream>>>(dec_bih, dec_bhh, bdP);
  pack_bias<<<16, b256, 0, stream>>>(cond_bih, cond_bhh, bcP);
  pack_zb<<<4096 * 512 / 1024, b256, 0, stream>>>(z, Zb);
  init_cond<<<256 * 1024 / 1024, b256, 0, stream>>>(cc, hz0);
  init_state<<<4096 * 1536 / 1024, b256, 0, stream>>>(dec_h0, dec_c0, Ab0, cdec);

  // Xz = Zb @ Wcih^T (bf16, X layout)
  gemm8<0><<<256, 512, 131072, stream>>>(Zb, 512, Wcih, 512, Xz,
                                         nullptr, nullptr, nullptr, nullptr, 0);

  // conductor chain: 16 sequential fused steps (M=256)
  for (int l = 0; l < 16; ++l) {
    const bf16* hprev = (l == 0) ? hz0 : (emb + (size_t)(l - 1) * 256 * 1024);
    gemm_cell<32, 2, 2, 2><<<dim3(32, 8), dim3(256), 0, stream>>>(
        hprev, 1024, Wchh, Xz + (size_t)l * 256 * 4096, bcP,
        cc, emb + (size_t)l * 256 * 1024, 1024, 1024);
  }

  // E = emb @ We^T (bf16, X layout)
  gemm8<0><<<256, 512, 131072, stream>>>(emb, 1024, We, 1024, E,
                                         nullptr, nullptr, nullptr, nullptr, 0);

  // 16 autoregressive decoder steps (M = 4096), ping-pong state (race-free)
  for (int n = 0; n < 16; ++n) {
    bf16* Sc = (n & 1) ? Ab1 : Ab0;
    bf16* Sn = (n & 1) ? Ab0 : Ab1;
    gemm8<1><<<256, 512, 131072, stream>>>(Sc, 1536, Wd, 1536, nullptr,
                                           E, bdP, cdec, Sn + 512, 1536);
    gemm_bt<128, 64, 2, 2, 1><<<dim3(512 / 64, 4096 / 128), dim3(256), 0, stream>>>(
        Sn + 512, 1536, Wo, 1024, nullptr, 0, 1024, out_b, out, Sn, n);
  }
}